// Round 2
// baseline (505.723 us; speedup 1.0000x reference)
//
#include <hip/hip_runtime.h>

// GCN 2-layer forward for MI355X (gfx950).
// Reference dtypes are float32, but the harness may have converted tensors to
// bf16 — we detect on-device (kdetect) and branch. Internals are canonical:
// x -> (bf16 MFMA) -> h1 bf16 [N,64] -> agg1+relu+GEMM2 -> h2 f32 [N,16]
// -> agg2+relu+log_softmax -> out (f32 or bf16 per mode).
//
// Pipeline:
//   memset degi, cursor
//   kdetect  : mode = 1 if float32 inputs else 0 (bf16)  [reads W1 bits]
//   kconvw   : canonicalize weights (W1->bf16, b1/W2/b2 -> f32)
//   kdeg     : degi[d] = #in-edges (int atomics)
//   kdinv    : dinv = (deg+1)^-0.5, dinv1 = 1/(deg+1)
//   kscan    : row_start = exclusive prefix sum of degi (single block)
//   kbucket  : CSR fill ebuf[pos] = {src, dinv[src]} via atomic cursor
//   kgemm1   : h1 = x @ W1 (bf16 out) via mfma_f32_16x16x32_bf16
//   kagg1    : per-node wave: relu(agg + self + b1) -> fused GEMM2 -> h2 f32
//   kagg2    : per-node quarter-wave: relu(agg + self + b2) -> log_softmax

typedef unsigned short u16;
typedef __attribute__((ext_vector_type(8))) short short8;   // 8 bf16 (4 VGPRs)
typedef __attribute__((ext_vector_type(4))) float f32x4;    // MFMA accum

__device__ __forceinline__ float bf2f(u16 u) {
  return __uint_as_float(((unsigned int)u) << 16);
}
__device__ __forceinline__ u16 f2bf(float f) {
  unsigned int u = __float_as_uint(f);
  u += 0x7fffu + ((u >> 16) & 1u);   // round-to-nearest-even
  return (u16)(u >> 16);
}

// ---- dtype detection: bf16-interp of f32 data has huge/NaN values ----
__global__ __launch_bounds__(256) void kdetect(const u16* __restrict__ w,
                                               int n16, int* __restrict__ mode) {
  __shared__ float red[4];
  float mx = 0.f;
  for (int i = threadIdx.x; i < n16; i += 256) {
    float av = fabsf(bf2f(w[i]));
    if (!(av <= 1e6f)) av = 3e38f;       // NaN or big -> flag
    mx = fmaxf(mx, av);
  }
  #pragma unroll
  for (int off = 32; off >= 1; off >>= 1) mx = fmaxf(mx, __shfl_xor(mx, off, 64));
  if ((threadIdx.x & 63) == 0) red[threadIdx.x >> 6] = mx;
  __syncthreads();
  if (threadIdx.x == 0) {
    float m2 = fmaxf(fmaxf(red[0], red[1]), fmaxf(red[2], red[3]));
    mode[0] = (m2 > 1e6f) ? 1 : 0;       // 1 = float32 inputs, 0 = bf16
  }
}

// ---- canonicalize weights into ws: W1 -> bf16[8192], b1/W2/b2 -> f32 ----
__global__ void kconvw(const void* __restrict__ W1r, const void* __restrict__ b1r,
                       const void* __restrict__ W2r, const void* __restrict__ b2r,
                       const int* __restrict__ mode, u16* __restrict__ W1b,
                       float* __restrict__ b1f, float* __restrict__ W2f,
                       float* __restrict__ b2f) {
  int m = mode[0];
  int gid = blockIdx.x * 256 + threadIdx.x, stride = gridDim.x * 256;
  for (int i = gid; i < 8192; i += stride)
    W1b[i] = m ? f2bf(((const float*)W1r)[i]) : ((const u16*)W1r)[i];
  for (int i = gid; i < 1024; i += stride)
    W2f[i] = m ? ((const float*)W2r)[i] : bf2f(((const u16*)W2r)[i]);
  for (int i = gid; i < 64; i += stride)
    b1f[i] = m ? ((const float*)b1r)[i] : bf2f(((const u16*)b1r)[i]);
  for (int i = gid; i < 16; i += stride)
    b2f[i] = m ? ((const float*)b2r)[i] : bf2f(((const u16*)b2r)[i]);
}

__global__ void kdeg(const int* __restrict__ dst, int* __restrict__ degi, int E) {
  int i = blockIdx.x * blockDim.x + threadIdx.x;
  if (i < E) atomicAdd(&degi[dst[i]], 1);
}

__global__ void kdinv(const int* __restrict__ degi, float* __restrict__ dinv,
                      float* __restrict__ dinv1, int n) {
  int i = blockIdx.x * blockDim.x + threadIdx.x;
  if (i < n) {
    float d = (float)(degi[i] + 1);
    dinv[i] = rsqrtf(d);
    dinv1[i] = 1.0f / d;
  }
}

// Single-block exclusive scan over n ints: wave shfl scan + LDS combine.
__global__ __launch_bounds__(1024) void kscan(const int* __restrict__ degi,
                                              int* __restrict__ row_start, int n) {
  __shared__ int wsum[16];
  __shared__ int wexcl[16];
  __shared__ int s_carry, s_total;
  int tid = threadIdx.x, lane = tid & 63, wv = tid >> 6;
  if (tid == 0) s_carry = 0;
  __syncthreads();
  for (int base = 0; base < n; base += 1024) {
    int i = base + tid;
    int v = (i < n) ? degi[i] : 0;
    int s = v;
    #pragma unroll
    for (int off = 1; off < 64; off <<= 1) {
      int t = __shfl_up(s, off, 64);
      if (lane >= off) s += t;
    }
    if (lane == 63) wsum[wv] = s;
    __syncthreads();
    if (tid < 16) {
      int ws = wsum[tid];
      int sc = ws;
      #pragma unroll
      for (int off = 1; off < 16; off <<= 1) {
        int t = __shfl_up(sc, off, 16);
        if (tid >= off) sc += t;
      }
      wexcl[tid] = sc - ws;
      if (tid == 15) s_total = sc;
    }
    __syncthreads();
    if (i < n) row_start[i] = s_carry + wexcl[wv] + (s - v);
    __syncthreads();
    if (tid == 0) s_carry += s_total;
    __syncthreads();
  }
  if (threadIdx.x == 0) row_start[n] = s_carry;
}

__global__ void kbucket(const int* __restrict__ src, const int* __restrict__ dst,
                        const int* __restrict__ row_start, int* __restrict__ cursor,
                        const float* __restrict__ dinv, int2* __restrict__ ebuf, int E) {
  int i = blockIdx.x * blockDim.x + threadIdx.x;
  if (i < E) {
    int s = src[i], d = dst[i];
    int pos = row_start[d] + atomicAdd(&cursor[d], 1);
    ebuf[pos] = make_int2(s, __float_as_int(dinv[s]));
  }
}

// h1 = x @ W1 : [N,128] x [128,64] -> bf16. One wave per 16-row tile.
// A frag: A[m=lane&15][k=quad*8+j]; B frag: B[k=quad*8+j][n=lane&15];
// C/D: col=lane&15, row=quad*4+reg  (learn_hip m89/m91-verified layouts).
__global__ __launch_bounds__(256) void kgemm1(const void* __restrict__ xraw,
                                              const u16* __restrict__ W1b,
                                              const int* __restrict__ mode,
                                              u16* __restrict__ h1, int n) {
  int mflag = mode[0];
  int wid = blockIdx.x * 4 + (threadIdx.x >> 6);
  int row0 = wid * 16;
  if (row0 >= n) return;
  int lane = threadIdx.x & 63;
  int m = lane & 15, q = lane >> 4;

  short8 bfrag[4][4];                     // [jb][kb] — W1 tiny, L1-hot
  for (int jb = 0; jb < 4; ++jb)
    for (int kb = 0; kb < 4; ++kb) {
      short8 f;
      #pragma unroll
      for (int j = 0; j < 8; ++j)
        f[j] = (short)W1b[(kb * 32 + q * 8 + j) * 64 + jb * 16 + m];
      bfrag[jb][kb] = f;
    }

  f32x4 acc[4];
  #pragma unroll
  for (int jb = 0; jb < 4; ++jb) acc[jb] = (f32x4){0.f, 0.f, 0.f, 0.f};

  #pragma unroll
  for (int kb = 0; kb < 4; ++kb) {
    short8 a;
    if (mflag) {
      const float* xf = (const float*)xraw + (size_t)(row0 + m) * 128 + kb * 32 + q * 8;
      float4 u0 = ((const float4*)xf)[0];
      float4 u1 = ((const float4*)xf)[1];
      a[0] = (short)f2bf(u0.x); a[1] = (short)f2bf(u0.y);
      a[2] = (short)f2bf(u0.z); a[3] = (short)f2bf(u0.w);
      a[4] = (short)f2bf(u1.x); a[5] = (short)f2bf(u1.y);
      a[6] = (short)f2bf(u1.z); a[7] = (short)f2bf(u1.w);
    } else {
      a = *(const short8*)((const u16*)xraw + (size_t)(row0 + m) * 128 + kb * 32 + q * 8);
    }
    #pragma unroll
    for (int jb = 0; jb < 4; ++jb)
      acc[jb] = __builtin_amdgcn_mfma_f32_16x16x32_bf16(a, bfrag[jb][kb], acc[jb], 0, 0, 0);
  }

  #pragma unroll
  for (int jb = 0; jb < 4; ++jb)
    #pragma unroll
    for (int r = 0; r < 4; ++r)
      h1[(size_t)(row0 + q * 4 + r) * 64 + jb * 16 + m] = f2bf(acc[jb][r]);
}

// Layer-1 aggregate + bias + relu, fused with GEMM2 (relu1 @ W2 -> h2 [N,16] f32).
// One wave per node; lane = feature j in [0,64).
__global__ __launch_bounds__(256) void kagg1(
    const u16* __restrict__ h1, const int2* __restrict__ ebuf,
    const int* __restrict__ row_start, const float* __restrict__ dinv,
    const float* __restrict__ dinv1, const float* __restrict__ b1f,
    const float* __restrict__ W2f, float* __restrict__ h2, int n) {
  __shared__ float W2s[64 * 17];          // padded stride 17: conflict-free
  __shared__ float rows[4][64];
  int tid = threadIdx.x;
  for (int i = tid; i < 1024; i += 256)
    W2s[(i >> 4) * 17 + (i & 15)] = W2f[i];
  __syncthreads();

  int lane = tid & 63, wv = tid >> 6;
  int node = blockIdx.x * 4 + wv;         // grid = N/4 exactly
  int beg = row_start[node], end = row_start[node + 1];
  float acc = 0.f;
  int e = beg;
  for (; e + 2 <= end; e += 2) {          // 2-wide for MLP
    int2 e0 = ebuf[e], e1 = ebuf[e + 1];
    float g0 = bf2f(h1[(size_t)e0.x * 64 + lane]);
    float g1 = bf2f(h1[(size_t)e1.x * 64 + lane]);
    acc = fmaf(__int_as_float(e0.y), g0, acc);
    acc = fmaf(__int_as_float(e1.y), g1, acc);
  }
  if (e < end) {
    int2 e0 = ebuf[e];
    acc = fmaf(__int_as_float(e0.y), bf2f(h1[(size_t)e0.x * 64 + lane]), acc);
  }
  float v = acc * dinv[node] + bf2f(h1[(size_t)node * 64 + lane]) * dinv1[node] + b1f[lane];
  v = fmaxf(v, 0.f);
  rows[wv][lane] = v;
  __syncthreads();

  // GEMM2: h2[node][c] = sum_j rows[j] * W2[j][c]; lane -> (c=lane&15, g=lane>>4)
  int c = lane & 15, g = lane >> 4;
  float p = 0.f;
  #pragma unroll
  for (int j0 = 0; j0 < 16; ++j0) {
    int j = g * 16 + j0;
    p = fmaf(rows[wv][j], W2s[j * 17 + c], p);
  }
  p += __shfl_xor(p, 16, 64);
  p += __shfl_xor(p, 32, 64);
  if (g == 0) h2[(size_t)node * 16 + c] = p;
}

// Layer-2 aggregate + bias + relu + log_softmax. Quarter-wave per node.
__global__ __launch_bounds__(256) void kagg2(
    const float* __restrict__ h2, const int2* __restrict__ ebuf,
    const int* __restrict__ row_start, const float* __restrict__ dinv,
    const float* __restrict__ dinv1, const float* __restrict__ b2f,
    const int* __restrict__ mode, void* __restrict__ out, int n) {
  int mflag = mode[0];
  int tid = threadIdx.x;
  int lane = tid & 63, wv = tid >> 6;
  int c = lane & 15, sub = lane >> 4;
  int node = blockIdx.x * 16 + wv * 4 + sub;   // grid = N/16 exactly
  int beg = row_start[node], end = row_start[node + 1];
  float acc = 0.f;
  int e = beg;
  for (; e + 2 <= end; e += 2) {
    int2 e0 = ebuf[e], e1 = ebuf[e + 1];
    acc = fmaf(__int_as_float(e0.y), h2[(size_t)e0.x * 16 + c], acc);
    acc = fmaf(__int_as_float(e1.y), h2[(size_t)e1.x * 16 + c], acc);
  }
  if (e < end) {
    int2 e0 = ebuf[e];
    acc = fmaf(__int_as_float(e0.y), h2[(size_t)e0.x * 16 + c], acc);
  }
  float v = acc * dinv[node] + h2[(size_t)node * 16 + c] * dinv1[node] + b2f[c];
  v = fmaxf(v, 0.f);

  float m = v;
  #pragma unroll
  for (int off = 8; off >= 1; off >>= 1) m = fmaxf(m, __shfl_xor(m, off, 16));
  float ex = __expf(v - m);
  float s = ex;
  #pragma unroll
  for (int off = 8; off >= 1; off >>= 1) s += __shfl_xor(s, off, 16);
  float r = v - m - __logf(s);
  size_t oidx = (size_t)node * 16 + c;
  if (mflag) ((float*)out)[oidx] = r;
  else       ((u16*)out)[oidx] = f2bf(r);
}

extern "C" void kernel_launch(void* const* d_in, const int* in_sizes, int n_in,
                              void* d_out, int out_size, void* d_ws, size_t ws_size,
                              hipStream_t stream) {
  const void* x  = d_in[0];
  const int* ei  = (const int*)d_in[1];
  const void* W1 = d_in[2];
  const void* b1 = d_in[3];
  const void* W2 = d_in[4];
  const void* b2 = d_in[5];

  const int N = in_sizes[0] / 128;
  const int E = in_sizes[1] / 2;
  const int* src = ei;
  const int* dst = ei + E;

  // workspace carve (256B aligned), total ~34 MB
  char* ws = (char*)d_ws;
  size_t off = 0;
  auto alloc = [&](size_t bytes) -> char* {
    char* p = ws + off;
    off = (off + bytes + 255) & ~(size_t)255;
    return p;
  };
  u16*   h1        = (u16*)  alloc((size_t)N * 64 * 2);
  float* h2        = (float*)alloc((size_t)N * 16 * 4);
  int2*  ebuf      = (int2*) alloc((size_t)E * 8);
  int*   degi      = (int*)  alloc((size_t)N * 4);
  float* dinv      = (float*)alloc((size_t)N * 4);
  float* dinv1     = (float*)alloc((size_t)N * 4);
  int*   row_start = (int*)  alloc((size_t)(N + 1) * 4);
  int*   cursor    = (int*)  alloc((size_t)N * 4);
  u16*   W1b       = (u16*)  alloc(8192 * 2);
  float* W2f       = (float*)alloc(1024 * 4);
  float* b1f       = (float*)alloc(64 * 4);
  float* b2f       = (float*)alloc(16 * 4);
  int*   mode      = (int*)  alloc(4);

  hipMemsetAsync(degi, 0, (size_t)N * 4, stream);
  hipMemsetAsync(cursor, 0, (size_t)N * 4, stream);

  kdetect<<<1, 256, 0, stream>>>((const u16*)W1, 8192, mode);
  kconvw<<<32, 256, 0, stream>>>(W1, b1, W2, b2, mode, W1b, b1f, W2f, b2f);

  kdeg<<<(E + 255) / 256, 256, 0, stream>>>(dst, degi, E);
  kdinv<<<(N + 255) / 256, 256, 0, stream>>>(degi, dinv, dinv1, N);
  kscan<<<1, 1024, 0, stream>>>(degi, row_start, N);
  kbucket<<<(E + 255) / 256, 256, 0, stream>>>(src, dst, row_start, cursor, dinv, ebuf, E);

  int tiles = (N + 15) / 16;
  kgemm1<<<(tiles + 3) / 4, 256, 0, stream>>>(x, W1b, mode, h1, N);
  kagg1<<<N / 4, 256, 0, stream>>>(h1, ebuf, row_start, dinv, dinv1, b1f, W2f, h2, N);
  kagg2<<<N / 16, 256, 0, stream>>>(h2, ebuf, row_start, dinv, dinv1, b2f, mode, d_out, N);
}

// Round 3
// 386.027 us; speedup vs baseline: 1.3101x; 1.3101x over previous
//
#include <hip/hip_runtime.h>

// GCN 2-layer forward for MI355X (gfx950).
// Dtype detected on-device (f32 vs bf16 harness conversion).
// Key algebraic trick: rows pre-scaled by dinv so aggregation is a plain sum:
//   h1s[j] = (x@W1)[j] * dinv[j]
//   relu1[i] = relu(dinv[i]*(sum_{j->i} h1s[j] + h1s[i]) + b1)
//   h2s[i] = (relu1 @ W2)[i] * dinv[i]
//   out[i] = log_softmax(dinv[i]*(sum h2s[j] + h2s[i]) + b2)
// => ebuf stores only src index (4B), no per-edge norm multiply.
//
// Pipeline: memset(degi,cursor); kdetect; kconvw; kdeg; ksc1/ksc2/ksc3(scan+dinv);
//           kbucket(CSR); kgemm1(MFMA, scaled bf16 out); kagg1(+fused GEMM2); kagg2.

typedef unsigned short u16;
typedef __attribute__((ext_vector_type(8))) short short8;   // 8 bf16
typedef __attribute__((ext_vector_type(4))) float f32x4;

__device__ __forceinline__ float bf2f(u16 u) {
  return __uint_as_float(((unsigned int)u) << 16);
}
__device__ __forceinline__ u16 f2bf(float f) {
  unsigned int u = __float_as_uint(f);
  u += 0x7fffu + ((u >> 16) & 1u);
  return (u16)(u >> 16);
}

// ---- dtype detection: bf16-reinterp of f32 data shows huge exponents ----
__global__ __launch_bounds__(256) void kdetect(const u16* __restrict__ w,
                                               int n16, int* __restrict__ mode) {
  __shared__ float red[4];
  float mx = 0.f;
  for (int i = threadIdx.x; i < n16; i += 256) {
    float av = fabsf(bf2f(w[i]));
    if (!(av <= 1e6f)) av = 3e38f;
    mx = fmaxf(mx, av);
  }
  #pragma unroll
  for (int off = 32; off >= 1; off >>= 1) mx = fmaxf(mx, __shfl_xor(mx, off, 64));
  if ((threadIdx.x & 63) == 0) red[threadIdx.x >> 6] = mx;
  __syncthreads();
  if (threadIdx.x == 0) {
    float m2 = fmaxf(fmaxf(red[0], red[1]), fmaxf(red[2], red[3]));
    mode[0] = (m2 > 1e6f) ? 1 : 0;       // 1 = float32 inputs, 0 = bf16
  }
}

__global__ void kconvw(const void* __restrict__ W1r, const void* __restrict__ b1r,
                       const void* __restrict__ W2r, const void* __restrict__ b2r,
                       const int* __restrict__ mode, u16* __restrict__ W1b,
                       float* __restrict__ b1f, float* __restrict__ W2f,
                       float* __restrict__ b2f) {
  int m = mode[0];
  int gid = blockIdx.x * 256 + threadIdx.x, stride = gridDim.x * 256;
  for (int i = gid; i < 8192; i += stride)
    W1b[i] = m ? f2bf(((const float*)W1r)[i]) : ((const u16*)W1r)[i];
  for (int i = gid; i < 1024; i += stride)
    W2f[i] = m ? ((const float*)W2r)[i] : bf2f(((const u16*)W2r)[i]);
  for (int i = gid; i < 64; i += stride)
    b1f[i] = m ? ((const float*)b1r)[i] : bf2f(((const u16*)b1r)[i]);
  for (int i = gid; i < 16; i += stride)
    b2f[i] = m ? ((const float*)b2r)[i] : bf2f(((const u16*)b2r)[i]);
}

__global__ void kdeg(const int* __restrict__ dst, int* __restrict__ degi, int E) {
  int i = blockIdx.x * blockDim.x + threadIdx.x;
  if (i < E) atomicAdd(&degi[dst[i]], 1);
}

// ---- hierarchical exclusive scan of degi (CHUNK=4096 per block) ----
__global__ __launch_bounds__(1024) void ksc1(const int* __restrict__ degi,
                                             int* __restrict__ psum, int n) {
  __shared__ int wsum[16];
  int tid = threadIdx.x, lane = tid & 63, wv = tid >> 6;
  int i0 = blockIdx.x * 4096 + tid * 4;
  int s = 0;
  #pragma unroll
  for (int j = 0; j < 4; ++j) s += (i0 + j < n) ? degi[i0 + j] : 0;
  #pragma unroll
  for (int off = 32; off >= 1; off >>= 1) s += __shfl_xor(s, off, 64);
  if (lane == 0) wsum[wv] = s;
  __syncthreads();
  if (tid == 0) {
    int t = 0;
    #pragma unroll
    for (int w = 0; w < 16; ++w) t += wsum[w];
    psum[blockIdx.x] = t;
  }
}

// scan psum in place -> exclusive; write row_start[n] = total. nchunks <= 1024.
__global__ __launch_bounds__(1024) void ksc2(int* __restrict__ psum, int nchunks,
                                             int* __restrict__ row_start, int n) {
  __shared__ int wsum[16], wexcl[16];
  int tid = threadIdx.x, lane = tid & 63, wv = tid >> 6;
  int v = (tid < nchunks) ? psum[tid] : 0;
  int s = v;
  #pragma unroll
  for (int off = 1; off < 64; off <<= 1) {
    int t = __shfl_up(s, off, 64);
    if (lane >= off) s += t;
  }
  if (lane == 63) wsum[wv] = s;
  __syncthreads();
  if (tid < 16) {
    int ws = wsum[tid], sc = ws;
    #pragma unroll
    for (int off = 1; off < 16; off <<= 1) {
      int t = __shfl_up(sc, off, 16);
      if (tid >= off) sc += t;
    }
    wexcl[tid] = sc - ws;
  }
  __syncthreads();
  int incl = wexcl[wv] + s;
  if (tid < nchunks) psum[tid] = incl - v;       // exclusive
  if (tid == nchunks - 1) row_start[n] = incl;   // total = E
}

// rescan chunk, write exclusive row_start; also dinv = (deg+1)^-0.5.
__global__ __launch_bounds__(1024) void ksc3(const int* __restrict__ degi,
                                             const int* __restrict__ psum,
                                             int* __restrict__ row_start,
                                             float* __restrict__ dinv, int n) {
  __shared__ int wsum[16], wexcl[16];
  int tid = threadIdx.x, lane = tid & 63, wv = tid >> 6;
  int i0 = blockIdx.x * 4096 + tid * 4;
  int v[4];
  #pragma unroll
  for (int j = 0; j < 4; ++j) v[j] = (i0 + j < n) ? degi[i0 + j] : 0;
  int tsum = v[0] + v[1] + v[2] + v[3];
  int s = tsum;
  #pragma unroll
  for (int off = 1; off < 64; off <<= 1) {
    int t = __shfl_up(s, off, 64);
    if (lane >= off) s += t;
  }
  if (lane == 63) wsum[wv] = s;
  __syncthreads();
  if (tid < 16) {
    int ws = wsum[tid], sc = ws;
    #pragma unroll
    for (int off = 1; off < 16; off <<= 1) {
      int t = __shfl_up(sc, off, 16);
      if (tid >= off) sc += t;
    }
    wexcl[tid] = sc - ws;
  }
  __syncthreads();
  int excl = psum[blockIdx.x] + wexcl[wv] + (s - tsum);
  #pragma unroll
  for (int j = 0; j < 4; ++j) {
    if (i0 + j < n) {
      row_start[i0 + j] = excl;
      dinv[i0 + j] = rsqrtf((float)(v[j] + 1));
    }
    excl += v[j];
  }
}

__global__ void kbucket(const int* __restrict__ src, const int* __restrict__ dst,
                        const int* __restrict__ row_start, int* __restrict__ cursor,
                        int* __restrict__ ebuf, int E) {
  int i = blockIdx.x * blockDim.x + threadIdx.x;
  if (i < E) {
    int d = dst[i];
    int pos = row_start[d] + atomicAdd(&cursor[d], 1);
    ebuf[pos] = src[i];
  }
}

// h1s = (x @ W1) * dinv[row], bf16 out. One wave per 16-row tile.
// A frag: A[m=lane&15][k=quad*8+j]; C/D: col=lane&15, row=quad*4+reg.
__global__ __launch_bounds__(256) void kgemm1(const void* __restrict__ xraw,
                                              const u16* __restrict__ W1b,
                                              const int* __restrict__ mode,
                                              const float* __restrict__ dinv,
                                              u16* __restrict__ h1s, int n) {
  int mflag = mode[0];
  int wid = blockIdx.x * 4 + (threadIdx.x >> 6);
  int row0 = wid * 16;
  if (row0 >= n) return;
  int lane = threadIdx.x & 63;
  int m = lane & 15, q = lane >> 4;

  short8 bfrag[4][4];
  for (int jb = 0; jb < 4; ++jb)
    for (int kb = 0; kb < 4; ++kb) {
      short8 f;
      #pragma unroll
      for (int j = 0; j < 8; ++j)
        f[j] = (short)W1b[(kb * 32 + q * 8 + j) * 64 + jb * 16 + m];
      bfrag[jb][kb] = f;
    }

  f32x4 acc[4];
  #pragma unroll
  for (int jb = 0; jb < 4; ++jb) acc[jb] = (f32x4){0.f, 0.f, 0.f, 0.f};

  #pragma unroll
  for (int kb = 0; kb < 4; ++kb) {
    short8 a;
    if (mflag) {
      const float* xf = (const float*)xraw + (size_t)(row0 + m) * 128 + kb * 32 + q * 8;
      float4 u0 = ((const float4*)xf)[0];
      float4 u1 = ((const float4*)xf)[1];
      a[0] = (short)f2bf(u0.x); a[1] = (short)f2bf(u0.y);
      a[2] = (short)f2bf(u0.z); a[3] = (short)f2bf(u0.w);
      a[4] = (short)f2bf(u1.x); a[5] = (short)f2bf(u1.y);
      a[6] = (short)f2bf(u1.z); a[7] = (short)f2bf(u1.w);
    } else {
      a = *(const short8*)((const u16*)xraw + (size_t)(row0 + m) * 128 + kb * 32 + q * 8);
    }
    #pragma unroll
    for (int jb = 0; jb < 4; ++jb)
      acc[jb] = __builtin_amdgcn_mfma_f32_16x16x32_bf16(a, bfrag[jb][kb], acc[jb], 0, 0, 0);
  }

  #pragma unroll
  for (int r = 0; r < 4; ++r) {
    float dv = dinv[row0 + q * 4 + r];
    #pragma unroll
    for (int jb = 0; jb < 4; ++jb)
      h1s[(row0 + q * 4 + r) * 64 + jb * 16 + m] = f2bf(acc[jb][r] * dv);
  }
}

// Layer-1 aggregate (plain sum of pre-scaled rows) + relu + fused GEMM2.
// One wave per node; lane = feature. Cooperative 64-wide edge-index loads.
__global__ __launch_bounds__(256) void kagg1(
    const u16* __restrict__ h1s, const int* __restrict__ ebuf,
    const int* __restrict__ row_start, const float* __restrict__ dinv,
    const float* __restrict__ b1f, const float* __restrict__ W2f,
    float* __restrict__ h2s, int n) {
  __shared__ float W2s[64 * 17];
  __shared__ float rows[4][64];
  int tid = threadIdx.x;
  for (int i = tid; i < 1024; i += 256)
    W2s[(i >> 4) * 17 + (i & 15)] = W2f[i];
  __syncthreads();

  int lane = tid & 63, wv = tid >> 6;
  int node = blockIdx.x * 4 + wv;               // grid = N/4
  int beg = row_start[node], end = row_start[node + 1];
  float acc = 0.f;
  for (int base = beg; base < end; base += 64) {
    int idx = base + lane;
    int eidx = ebuf[(idx < end) ? idx : beg];   // coalesced 64-wide
    int cnt = min(64, end - base);
    int k = 0;
    for (; k + 4 <= cnt; k += 4) {
      int s0 = __shfl(eidx, k, 64), s1 = __shfl(eidx, k + 1, 64);
      int s2 = __shfl(eidx, k + 2, 64), s3 = __shfl(eidx, k + 3, 64);
      float g0 = bf2f(h1s[s0 * 64 + lane]);
      float g1 = bf2f(h1s[s1 * 64 + lane]);
      float g2 = bf2f(h1s[s2 * 64 + lane]);
      float g3 = bf2f(h1s[s3 * 64 + lane]);
      acc += (g0 + g1) + (g2 + g3);
    }
    for (; k < cnt; ++k) {
      int s0 = __shfl(eidx, k, 64);
      acc += bf2f(h1s[s0 * 64 + lane]);
    }
  }
  float v = dinv[node] * (acc + bf2f(h1s[node * 64 + lane])) + b1f[lane];
  v = fmaxf(v, 0.f);
  rows[wv][lane] = v;
  __syncthreads();

  // GEMM2: p[c] = sum_j rows[j]*W2[j][c]; then scale by dinv[node] -> h2s
  int c = lane & 15, g = lane >> 4;
  float p = 0.f;
  #pragma unroll
  for (int j0 = 0; j0 < 16; ++j0) {
    int j = g * 16 + j0;
    p = fmaf(rows[wv][j], W2s[j * 17 + c], p);
  }
  p += __shfl_xor(p, 16, 64);
  p += __shfl_xor(p, 32, 64);
  if (g == 0) h2s[node * 16 + c] = p * dinv[node];
}

// Layer-2 aggregate + bias + relu + log_softmax. Quarter-wave per node.
__global__ __launch_bounds__(256) void kagg2(
    const float* __restrict__ h2s, const int* __restrict__ ebuf,
    const int* __restrict__ row_start, const float* __restrict__ dinv,
    const float* __restrict__ b2f, const int* __restrict__ mode,
    void* __restrict__ out, int n) {
  int mflag = mode[0];
  int tid = threadIdx.x;
  int lane = tid & 63, wv = tid >> 6;
  int c = lane & 15, sub = lane >> 4;
  int node = blockIdx.x * 16 + wv * 4 + sub;    // grid = N/16
  int beg = row_start[node], end = row_start[node + 1];
  float acc = 0.f;
  for (int base = beg; base < end; base += 16) {
    int idx = base + c;
    int eidx = ebuf[(idx < end) ? idx : beg];   // coalesced 16-wide
    int cnt = min(16, end - base);
    int k = 0;
    for (; k + 4 <= cnt; k += 4) {
      int s0 = __shfl(eidx, k, 16), s1 = __shfl(eidx, k + 1, 16);
      int s2 = __shfl(eidx, k + 2, 16), s3 = __shfl(eidx, k + 3, 16);
      float g0 = h2s[s0 * 16 + c], g1 = h2s[s1 * 16 + c];
      float g2 = h2s[s2 * 16 + c], g3 = h2s[s3 * 16 + c];
      acc += (g0 + g1) + (g2 + g3);
    }
    for (; k < cnt; ++k) {
      int s0 = __shfl(eidx, k, 16);
      acc += h2s[s0 * 16 + c];
    }
  }
  float v = dinv[node] * (acc + h2s[node * 16 + c]) + b2f[c];
  v = fmaxf(v, 0.f);

  float m = v;
  #pragma unroll
  for (int off = 8; off >= 1; off >>= 1) m = fmaxf(m, __shfl_xor(m, off, 16));
  float ex = __expf(v - m);
  float s = ex;
  #pragma unroll
  for (int off = 8; off >= 1; off >>= 1) s += __shfl_xor(s, off, 16);
  float r = v - m - __logf(s);
  size_t oidx = (size_t)node * 16 + c;
  if (mflag) ((float*)out)[oidx] = r;
  else       ((u16*)out)[oidx] = f2bf(r);
}

extern "C" void kernel_launch(void* const* d_in, const int* in_sizes, int n_in,
                              void* d_out, int out_size, void* d_ws, size_t ws_size,
                              hipStream_t stream) {
  const void* x  = d_in[0];
  const int* ei  = (const int*)d_in[1];
  const void* W1 = d_in[2];
  const void* b1 = d_in[3];
  const void* W2 = d_in[4];
  const void* b2 = d_in[5];

  const int N = in_sizes[0] / 128;
  const int E = in_sizes[1] / 2;
  const int* src = ei;
  const int* dst = ei + E;
  const int nchunks = (N + 4095) / 4096;

  char* ws = (char*)d_ws;
  size_t off = 0;
  auto alloc = [&](size_t bytes) -> char* {
    char* p = ws + off;
    off = (off + bytes + 255) & ~(size_t)255;
    return p;
  };
  u16*   h1s       = (u16*)  alloc((size_t)N * 64 * 2);
  float* h2s       = (float*)alloc((size_t)N * 16 * 4);
  int*   ebuf      = (int*)  alloc((size_t)E * 4);
  int*   degi      = (int*)  alloc((size_t)N * 4);
  float* dinv      = (float*)alloc((size_t)N * 4);
  int*   row_start = (int*)  alloc((size_t)(N + 1) * 4);
  int*   cursor    = (int*)  alloc((size_t)N * 4);
  int*   psum      = (int*)  alloc((size_t)nchunks * 4);
  u16*   W1b       = (u16*)  alloc(8192 * 2);
  float* W2f       = (float*)alloc(1024 * 4);
  float* b1f       = (float*)alloc(64 * 4);
  float* b2f       = (float*)alloc(16 * 4);
  int*   mode      = (int*)  alloc(4);

  hipMemsetAsync(degi, 0, (size_t)N * 4, stream);
  hipMemsetAsync(cursor, 0, (size_t)N * 4, stream);

  kdetect<<<1, 256, 0, stream>>>((const u16*)W1, 8192, mode);
  kconvw<<<32, 256, 0, stream>>>(W1, b1, W2, b2, mode, W1b, b1f, W2f, b2f);

  kdeg<<<(E + 255) / 256, 256, 0, stream>>>(dst, degi, E);
  ksc1<<<nchunks, 1024, 0, stream>>>(degi, psum, N);
  ksc2<<<1, 1024, 0, stream>>>(psum, nchunks, row_start, N);
  ksc3<<<nchunks, 1024, 0, stream>>>(degi, psum, row_start, dinv, N);
  kbucket<<<(E + 255) / 256, 256, 0, stream>>>(src, dst, row_start, cursor, ebuf, E);

  int tiles = (N + 15) / 16;
  kgemm1<<<(tiles + 3) / 4, 256, 0, stream>>>(x, W1b, mode, dinv, h1s, N);
  kagg1<<<N / 4, 256, 0, stream>>>(h1s, ebuf, row_start, dinv, b1f, W2f, h2s, N);
  kagg2<<<N / 16, 256, 0, stream>>>(h2s, ebuf, row_start, dinv, b2f, mode, d_out, N);
}